// Round 1
// baseline (265.356 us; speedup 1.0000x reference)
//
#include <hip/hip_runtime.h>

// DLRM interact_features, B=1, D=16777216, 4 features (x, ly_0, ly_1, ly_2).
// out[0..D-1] = x;  out[D..D+5] = [x.l0, x.l1, l0.l1, x.l2, l0.l2, l1.l2]
// (strict lower-triangular order of Z = T T^T with T rows [x, l0, l1, l2]).

constexpr int D_TOTAL = 16777216;
constexpr int NVEC    = D_TOTAL / 4;   // float4 elements
constexpr int BLOCK   = 256;
constexpr int GRID    = 2048;          // ~8 blocks/CU, grid-stride covers the rest

__global__ void dlrm_init_pairs(float* __restrict__ out) {
    if (threadIdx.x < 6) out[(size_t)D_TOTAL + threadIdx.x] = 0.0f;
}

__global__ __launch_bounds__(BLOCK) void dlrm_interact_kernel(
        const float4* __restrict__ x,
        const float4* __restrict__ l0,
        const float4* __restrict__ l1,
        const float4* __restrict__ l2,
        float4* __restrict__ out_copy,   // = out, viewed as float4 (D/4 elems)
        float*  __restrict__ out_pairs)  // = out + D (6 floats)
{
    float s[6] = {0.f, 0.f, 0.f, 0.f, 0.f, 0.f};

    for (int i = blockIdx.x * BLOCK + threadIdx.x; i < NVEC; i += BLOCK * GRID) {
        const float4 vx = x[i];
        const float4 v0 = l0[i];
        const float4 v1 = l1[i];
        const float4 v2 = l2[i];
        out_copy[i] = vx;
        // pair order: (1,0) (2,0) (2,1) (3,0) (3,1) (3,2) with rows {0:x,1:l0,2:l1,3:l2}
        s[0] += vx.x*v0.x + vx.y*v0.y + vx.z*v0.z + vx.w*v0.w;  // x  . l0
        s[1] += vx.x*v1.x + vx.y*v1.y + vx.z*v1.z + vx.w*v1.w;  // x  . l1
        s[2] += v0.x*v1.x + v0.y*v1.y + v0.z*v1.z + v0.w*v1.w;  // l0 . l1
        s[3] += vx.x*v2.x + vx.y*v2.y + vx.z*v2.z + vx.w*v2.w;  // x  . l2
        s[4] += v0.x*v2.x + v0.y*v2.y + v0.z*v2.z + v0.w*v2.w;  // l0 . l2
        s[5] += v1.x*v2.x + v1.y*v2.y + v1.z*v2.z + v1.w*v2.w;  // l1 . l2
    }

    // wave-64 butterfly reduction of all 6 partials
    #pragma unroll
    for (int off = 32; off > 0; off >>= 1) {
        #pragma unroll
        for (int k = 0; k < 6; ++k)
            s[k] += __shfl_down(s[k], off, 64);
    }

    // cross-wave reduction via LDS (4 waves per block)
    __shared__ float red[BLOCK / 64][6];
    const int wave = threadIdx.x >> 6;
    const int lane = threadIdx.x & 63;
    if (lane == 0) {
        #pragma unroll
        for (int k = 0; k < 6; ++k) red[wave][k] = s[k];
    }
    __syncthreads();

    if (threadIdx.x < 6) {
        float tot = 0.f;
        #pragma unroll
        for (int w = 0; w < BLOCK / 64; ++w) tot += red[w][threadIdx.x];
        atomicAdd(out_pairs + threadIdx.x, tot);
    }
}

extern "C" void kernel_launch(void* const* d_in, const int* in_sizes, int n_in,
                              void* d_out, int out_size, void* d_ws, size_t ws_size,
                              hipStream_t stream) {
    const float4* x  = (const float4*)d_in[0];
    const float4* l0 = (const float4*)d_in[1];
    const float4* l1 = (const float4*)d_in[2];
    const float4* l2 = (const float4*)d_in[3];
    float* out = (float*)d_out;

    dlrm_init_pairs<<<1, 64, 0, stream>>>(out);
    dlrm_interact_kernel<<<GRID, BLOCK, 0, stream>>>(
        x, l0, l1, l2, (float4*)out, out + (size_t)D_TOTAL);
}

// Round 4
// 265.035 us; speedup vs baseline: 1.0012x; 1.0012x over previous
//
#include <hip/hip_runtime.h>

// DLRM interact_features, B=1, D=16777216, 4 features (x, ly_0, ly_1, ly_2).
// out[0..D-1] = x;  out[D..D+5] = [x.l0, x.l1, l0.l1, x.l2, l0.l2, l1.l2]

typedef float fvec4 __attribute__((ext_vector_type(4)));

constexpr int D_TOTAL = 16777216;
constexpr int NVEC    = D_TOTAL / 4;           // fvec4 elements = 4194304
constexpr int BLOCK   = 256;
constexpr int GRID    = 2048;
constexpr int ITERS   = NVEC / (BLOCK * GRID); // exactly 8
static_assert(NVEC == BLOCK * GRID * ITERS, "exact tiling");

#define FMA4(acc, u, v) \
    acc += u.x * v.x + u.y * v.y + u.z * v.z + u.w * v.w;

__global__ __launch_bounds__(BLOCK) void dlrm_interact_main(
        const fvec4* __restrict__ x,
        const fvec4* __restrict__ l0,
        const fvec4* __restrict__ l1,
        const fvec4* __restrict__ l2,
        fvec4* __restrict__ out_copy,
        float* __restrict__ partials)  // [6][GRID]
{
    float s[6] = {0.f, 0.f, 0.f, 0.f, 0.f, 0.f};

    const int base   = blockIdx.x * BLOCK + threadIdx.x;
    const int stride = BLOCK * GRID;

    // 2-way unrolled, compile-time trip count: 8 loads in flight per step.
    #pragma unroll
    for (int it = 0; it < ITERS; it += 2) {
        const int i0 = base + it * stride;
        const int i1 = i0 + stride;
        const fvec4 a0 = x[i0],  a1 = x[i1];
        const fvec4 b0 = l0[i0], b1 = l0[i1];
        const fvec4 c0 = l1[i0], c1 = l1[i1];
        const fvec4 d0 = l2[i0], d1 = l2[i1];
        __builtin_nontemporal_store(a0, &out_copy[i0]);
        __builtin_nontemporal_store(a1, &out_copy[i1]);
        FMA4(s[0], a0, b0)  FMA4(s[0], a1, b1)   // x  . l0
        FMA4(s[1], a0, c0)  FMA4(s[1], a1, c1)   // x  . l1
        FMA4(s[2], b0, c0)  FMA4(s[2], b1, c1)   // l0 . l1
        FMA4(s[3], a0, d0)  FMA4(s[3], a1, d1)   // x  . l2
        FMA4(s[4], b0, d0)  FMA4(s[4], b1, d1)   // l0 . l2
        FMA4(s[5], c0, d0)  FMA4(s[5], c1, d1)   // l1 . l2
    }

    // wave-64 butterfly reduction of all 6 partials
    #pragma unroll
    for (int off = 32; off > 0; off >>= 1) {
        #pragma unroll
        for (int k = 0; k < 6; ++k)
            s[k] += __shfl_down(s[k], off, 64);
    }

    // cross-wave reduction via LDS (4 waves per block), then ONE plain store
    // per pair per block into the partials buffer (no atomics).
    __shared__ float red[BLOCK / 64][6];
    const int wave = threadIdx.x >> 6;
    const int lane = threadIdx.x & 63;
    if (lane == 0) {
        #pragma unroll
        for (int k = 0; k < 6; ++k) red[wave][k] = s[k];
    }
    __syncthreads();

    if (threadIdx.x < 6) {
        float tot = 0.f;
        #pragma unroll
        for (int w = 0; w < BLOCK / 64; ++w) tot += red[w][threadIdx.x];
        partials[threadIdx.x * GRID + blockIdx.x] = tot;
    }
}

// 6 waves, wave k sums partials[k][0..GRID) and writes out_pairs[k].
__global__ __launch_bounds__(384) void dlrm_reduce(
        const float* __restrict__ partials, float* __restrict__ out_pairs)
{
    const int w    = threadIdx.x >> 6;
    const int lane = threadIdx.x & 63;
    const float* row = partials + w * GRID;
    float s = 0.f;
    #pragma unroll
    for (int i = 0; i < GRID / 64; ++i) s += row[lane + i * 64];
    #pragma unroll
    for (int off = 32; off > 0; off >>= 1) s += __shfl_down(s, off, 64);
    if (lane == 0) out_pairs[w] = s;
}

// ---- fallback path (ws too small): atomic version ----
__global__ void dlrm_init_pairs(float* __restrict__ out) {
    if (threadIdx.x < 6) out[(size_t)D_TOTAL + threadIdx.x] = 0.0f;
}

__global__ __launch_bounds__(BLOCK) void dlrm_interact_atomic(
        const fvec4* __restrict__ x, const fvec4* __restrict__ l0,
        const fvec4* __restrict__ l1, const fvec4* __restrict__ l2,
        fvec4* __restrict__ out_copy, float* __restrict__ out_pairs)
{
    float s[6] = {0.f, 0.f, 0.f, 0.f, 0.f, 0.f};
    const int base = blockIdx.x * BLOCK + threadIdx.x;
    const int stride = BLOCK * GRID;
    #pragma unroll
    for (int it = 0; it < ITERS; ++it) {
        const int i = base + it * stride;
        const fvec4 a = x[i], b = l0[i], c = l1[i], d = l2[i];
        out_copy[i] = a;
        FMA4(s[0], a, b) FMA4(s[1], a, c) FMA4(s[2], b, c)
        FMA4(s[3], a, d) FMA4(s[4], b, d) FMA4(s[5], c, d)
    }
    #pragma unroll
    for (int off = 32; off > 0; off >>= 1)
        #pragma unroll
        for (int k = 0; k < 6; ++k) s[k] += __shfl_down(s[k], off, 64);
    __shared__ float red[BLOCK / 64][6];
    const int wave = threadIdx.x >> 6, lane = threadIdx.x & 63;
    if (lane == 0)
        for (int k = 0; k < 6; ++k) red[wave][k] = s[k];
    __syncthreads();
    if (threadIdx.x < 6) {
        float tot = 0.f;
        for (int w = 0; w < BLOCK / 64; ++w) tot += red[w][threadIdx.x];
        atomicAdd(out_pairs + threadIdx.x, tot);
    }
}

extern "C" void kernel_launch(void* const* d_in, const int* in_sizes, int n_in,
                              void* d_out, int out_size, void* d_ws, size_t ws_size,
                              hipStream_t stream) {
    const fvec4* x  = (const fvec4*)d_in[0];
    const fvec4* l0 = (const fvec4*)d_in[1];
    const fvec4* l1 = (const fvec4*)d_in[2];
    const fvec4* l2 = (const fvec4*)d_in[3];
    float* out = (float*)d_out;

    if (ws_size >= (size_t)6 * GRID * sizeof(float)) {
        float* partials = (float*)d_ws;
        dlrm_interact_main<<<GRID, BLOCK, 0, stream>>>(
            x, l0, l1, l2, (fvec4*)out, partials);
        dlrm_reduce<<<1, 384, 0, stream>>>(partials, out + (size_t)D_TOTAL);
    } else {
        dlrm_init_pairs<<<1, 64, 0, stream>>>(out);
        dlrm_interact_atomic<<<GRID, BLOCK, 0, stream>>>(
            x, l0, l1, l2, (fvec4*)out, out + (size_t)D_TOTAL);
    }
}